// Round 1
// baseline (734.795 us; speedup 1.0000x reference)
//
#include <hip/hip_runtime.h>

typedef unsigned short ushort_t;
typedef __attribute__((ext_vector_type(8))) short short8;
typedef __attribute__((ext_vector_type(4))) float f32x4;

#define B_ 4
#define T_ 2048
#define D_ 1024
#define F_ 4096
#define M_ (B_*T_)

#define AS1 __attribute__((address_space(1)))
#define AS3 __attribute__((address_space(3)))

__device__ __forceinline__ ushort_t f2bf(float f) {
  union { float f; unsigned u; } a; a.f = f;
  unsigned r = a.u + 0x7FFFu + ((a.u >> 16) & 1u);
  return (ushort_t)(r >> 16);
}

__device__ __forceinline__ void gl_lds16(const void* g, void* l) {
  __builtin_amdgcn_global_load_lds((AS1 void*)(__UINTPTR_TYPE__)g,
                                   (AS3 void*)l, 16, 0, 0);
}

// ---------------- transpose + f32->bf16 convert: Wt[n][k] = W[k][n] ----------------
__global__ __launch_bounds__(256) void tconv(const float* __restrict__ W,
                                             ushort_t* __restrict__ Wt,
                                             int K, int N) {
  __shared__ float tile[32][33];
  int tx = threadIdx.x, ty = threadIdx.y;
  int n0 = blockIdx.x * 32, k0 = blockIdx.y * 32;
  #pragma unroll
  for (int i = 0; i < 32; i += 8)
    tile[ty + i][tx] = W[(size_t)(k0 + ty + i) * N + n0 + tx];
  __syncthreads();
  #pragma unroll
  for (int i = 0; i < 32; i += 8)
    Wt[(size_t)(n0 + ty + i) * K + k0 + tx] = f2bf(tile[tx][ty + i]);
}

// ---------------- LayerNorm (one block per row of 1024) ----------------
__global__ __launch_bounds__(256) void ln_fwd(const float* __restrict__ x,
                                              const float* __restrict__ g,
                                              const float* __restrict__ bb,
                                              float* __restrict__ h,
                                              float* __restrict__ last) {
  int row = blockIdx.x;
  int tid = threadIdx.x;
  float4 v = ((const float4*)(x + (size_t)row * D_))[tid];
  float s1 = v.x + v.y + v.z + v.w;
  float s2 = v.x * v.x + v.y * v.y + v.z * v.z + v.w * v.w;
  #pragma unroll
  for (int o = 32; o > 0; o >>= 1) { s1 += __shfl_down(s1, o); s2 += __shfl_down(s2, o); }
  __shared__ float r1[4], r2[4];
  if ((tid & 63) == 0) { r1[tid >> 6] = s1; r2[tid >> 6] = s2; }
  __syncthreads();
  s1 = r1[0] + r1[1] + r1[2] + r1[3];
  s2 = r2[0] + r2[1] + r2[2] + r2[3];
  float mu = s1 * (1.0f / D_);
  float rs = rsqrtf(s2 * (1.0f / D_) - mu * mu + 1e-3f);
  float4 gv = ((const float4*)g)[tid];
  float4 bv = ((const float4*)bb)[tid];
  float4 o4;
  o4.x = (v.x - mu) * rs * gv.x + bv.x;
  o4.y = (v.y - mu) * rs * gv.y + bv.y;
  o4.z = (v.z - mu) * rs * gv.z + bv.z;
  o4.w = (v.w - mu) * rs * gv.w + bv.w;
  ((float4*)(h + (size_t)row * D_))[tid] = o4;
  if ((row & (T_ - 1)) == T_ - 1)
    ((float4*)(last + (size_t)(row >> 11) * D_))[tid] = o4;
}

// ---------------- token-shift mixes (f32 in, bf16 out) ----------------
#define MIX1(c, p, f) f2bf((c) * (f) + (p) * (1.0f - (f)))

__global__ __launch_bounds__(256) void mix_tm(const float* __restrict__ h,
                                              const float* __restrict__ st,
                                              const float* __restrict__ mk,
                                              const float* __restrict__ mv,
                                              const float* __restrict__ mr,
                                              ushort_t* __restrict__ xk,
                                              ushort_t* __restrict__ xv,
                                              ushort_t* __restrict__ xr) {
  size_t qi = (size_t)blockIdx.x * 256 + threadIdx.x;  // float4 index
  int dq = (int)(qi & 255);
  size_t td = qi >> 8;
  int t = (int)(td & (T_ - 1));
  int b = (int)(td >> 11);
  float4 hc = ((const float4*)h)[qi];
  float4 hp = (t == 0) ? ((const float4*)st)[b * 256 + dq] : ((const float4*)h)[qi - 256];
  float4 k4 = ((const float4*)mk)[dq];
  float4 v4 = ((const float4*)mv)[dq];
  float4 r4 = ((const float4*)mr)[dq];
  ushort4 ok, ov, orr;
  ok.x = MIX1(hc.x, hp.x, k4.x); ok.y = MIX1(hc.y, hp.y, k4.y);
  ok.z = MIX1(hc.z, hp.z, k4.z); ok.w = MIX1(hc.w, hp.w, k4.w);
  ov.x = MIX1(hc.x, hp.x, v4.x); ov.y = MIX1(hc.y, hp.y, v4.y);
  ov.z = MIX1(hc.z, hp.z, v4.z); ov.w = MIX1(hc.w, hp.w, v4.w);
  orr.x = MIX1(hc.x, hp.x, r4.x); orr.y = MIX1(hc.y, hp.y, r4.y);
  orr.z = MIX1(hc.z, hp.z, r4.z); orr.w = MIX1(hc.w, hp.w, r4.w);
  ((ushort4*)xk)[qi] = ok;
  ((ushort4*)xv)[qi] = ov;
  ((ushort4*)xr)[qi] = orr;
}

__global__ __launch_bounds__(256) void mix_cm(const float* __restrict__ h,
                                              const float* __restrict__ st,
                                              const float* __restrict__ mk,
                                              const float* __restrict__ mr,
                                              ushort_t* __restrict__ xk,
                                              ushort_t* __restrict__ xr) {
  size_t qi = (size_t)blockIdx.x * 256 + threadIdx.x;
  int dq = (int)(qi & 255);
  size_t td = qi >> 8;
  int t = (int)(td & (T_ - 1));
  int b = (int)(td >> 11);
  float4 hc = ((const float4*)h)[qi];
  float4 hp = (t == 0) ? ((const float4*)st)[b * 256 + dq] : ((const float4*)h)[qi - 256];
  float4 k4 = ((const float4*)mk)[dq];
  float4 r4 = ((const float4*)mr)[dq];
  ushort4 ok, orr;
  ok.x = MIX1(hc.x, hp.x, k4.x); ok.y = MIX1(hc.y, hp.y, k4.y);
  ok.z = MIX1(hc.z, hp.z, k4.z); ok.w = MIX1(hc.w, hp.w, k4.w);
  orr.x = MIX1(hc.x, hp.x, r4.x); orr.y = MIX1(hc.y, hp.y, r4.y);
  orr.z = MIX1(hc.z, hp.z, r4.z); orr.w = MIX1(hc.w, hp.w, r4.w);
  ((ushort4*)xk)[qi] = ok;
  ((ushort4*)xr)[qi] = orr;
}

// ---------------- WKV sequential scan: 1 thread per (b,d) channel ----------------
__global__ __launch_bounds__(256) void wkv_scan(const float* __restrict__ k,
                                                const float* __restrict__ v,
                                                const float* __restrict__ r,
                                                const float* __restrict__ sn,
                                                const float* __restrict__ sd,
                                                const float* __restrict__ sq,
                                                const float* __restrict__ tdec,
                                                const float* __restrict__ tfirst,
                                                ushort_t* __restrict__ rwkv,
                                                float* __restrict__ on,
                                                float* __restrict__ od,
                                                float* __restrict__ oq) {
  int idx = blockIdx.x * 256 + threadIdx.x;  // 0..4095
  int d = idx & (D_ - 1);
  int b = idx >> 10;
  float num = sn[idx], den = sd[idx], q = sq[idx];
  float w = -__expf(tdec[d]);
  float tf = tfirst[d];
  const float* kp = k + (size_t)b * T_ * D_ + d;
  const float* vp = v + (size_t)b * T_ * D_ + d;
  const float* rp = r + (size_t)b * T_ * D_ + d;
  ushort_t* op = rwkv + (size_t)b * T_ * D_ + d;
  for (int t0 = 0; t0 < T_; t0 += 8) {
    float kt[8], vt[8], rt[8];
    #pragma unroll
    for (int i = 0; i < 8; ++i) {
      size_t off = (size_t)(t0 + i) * D_;
      kt[i] = kp[off]; vt[i] = vp[off]; rt[i] = rp[off];
    }
    #pragma unroll
    for (int i = 0; i < 8; ++i) {
      float kk = kt[i];
      float mo = fmaxf(q, kk + tf);
      float e1 = __expf(q - mo), e2 = __expf(kk + tf - mo);
      float o = (e1 * num + e2 * vt[i]) / (e1 * den + e2);
      op[(size_t)(t0 + i) * D_] = f2bf(rt[i] * o);
      float ms = fmaxf(q + w, kk);
      float e1s = __expf(q + w - ms), e2s = __expf(kk - ms);
      num = e1s * num + e2s * vt[i];
      den = e1s * den + e2s;
      q = ms;
    }
  }
  on[idx] = num; od[idx] = den; oq[idx] = q;
}

// ---------------- 128x128 bf16 MFMA GEMM, B pre-transposed [N][K] ----------------
// EPI: 0 = f32 store, 1 = sigmoid f32, 2 = X + acc (f32), 3 = relu(acc)^2 -> bf16,
//      4 = X2 + sigmoid(acc)*X (f32, in-place capable)
template <int EPI>
__global__ __launch_bounds__(256)
void gemm128(const ushort_t* __restrict__ A, const ushort_t* __restrict__ Bt,
             int N, int K,
             float* __restrict__ Cf, ushort_t* __restrict__ Cb,
             const float* __restrict__ X, const float* __restrict__ X2) {
  __shared__ alignas(16) ushort_t sA[128 * 64];
  __shared__ alignas(16) ushort_t sB[128 * 64];
  const int tid = threadIdx.x;
  const int m0 = blockIdx.x * 128, n0 = blockIdx.y * 128;
  const int lane = tid & 63, wave = tid >> 6;
  const int wm = (wave >> 1) * 64, wn = (wave & 1) * 64;
  const int lr = lane & 15;
  const int lk = (lane >> 4) * 8;

  const ushort_t* ga = A + (size_t)(m0 + (tid >> 3)) * K + (tid & 7) * 8;
  const ushort_t* gb = Bt + (size_t)(n0 + (tid >> 3)) * K + (tid & 7) * 8;
  ushort_t* la = sA + tid * 8;
  ushort_t* lb = sB + tid * 8;

  f32x4 acc[4][4] = {};

  const int ksteps = K >> 6;
  for (int kt = 0; kt < ksteps; ++kt) {
    const int kof = kt * 64;
    #pragma unroll
    for (int i = 0; i < 4; ++i) {
      gl_lds16(ga + (size_t)(i * 32) * K + kof, la + i * 2048);
      gl_lds16(gb + (size_t)(i * 32) * K + kof, lb + i * 2048);
    }
    __syncthreads();
    short8 af[2][4], bfr[2][4];
    #pragma unroll
    for (int s = 0; s < 2; ++s)
      #pragma unroll
      for (int i = 0; i < 4; ++i) {
        af[s][i]  = *(const short8*)&sA[(wm + i * 16 + lr) * 64 + s * 32 + lk];
        bfr[s][i] = *(const short8*)&sB[(wn + i * 16 + lr) * 64 + s * 32 + lk];
      }
    #pragma unroll
    for (int s = 0; s < 2; ++s)
      #pragma unroll
      for (int mi = 0; mi < 4; ++mi)
        #pragma unroll
        for (int ni = 0; ni < 4; ++ni)
          acc[mi][ni] = __builtin_amdgcn_mfma_f32_16x16x32_bf16(
              af[s][mi], bfr[s][ni], acc[mi][ni], 0, 0, 0);
    __syncthreads();
  }

  #pragma unroll
  for (int mi = 0; mi < 4; ++mi)
    #pragma unroll
    for (int ni = 0; ni < 4; ++ni)
      #pragma unroll
      for (int j = 0; j < 4; ++j) {
        int row = m0 + wm + mi * 16 + ((lane >> 4) << 2) + j;
        int col = n0 + wn + ni * 16 + lr;
        size_t idx = (size_t)row * N + col;
        float v = acc[mi][ni][j];
        if (EPI == 0) {
          Cf[idx] = v;
        } else if (EPI == 1) {
          Cf[idx] = 1.0f / (1.0f + __expf(-v));
        } else if (EPI == 2) {
          Cf[idx] = X[idx] + v;
        } else if (EPI == 3) {
          float t = v > 0.0f ? v : 0.0f;
          Cb[idx] = f2bf(t * t);
        } else if (EPI == 4) {
          float s = 1.0f / (1.0f + __expf(-v));
          Cf[idx] = X2[idx] + s * X[idx];
        }
      }
}

// ---------------- launcher ----------------
extern "C" void kernel_launch(void* const* d_in, const int* in_sizes, int n_in,
                              void* d_out, int out_size, void* d_ws, size_t ws_size,
                              hipStream_t stream) {
  const float* x      = (const float*)d_in[0];
  const float* s_cm   = (const float*)d_in[1];
  const float* s_tm   = (const float*)d_in[2];
  const float* s_num  = (const float*)d_in[3];
  const float* s_den  = (const float*)d_in[4];
  const float* s_q    = (const float*)d_in[5];
  const float* ln1_g  = (const float*)d_in[6];
  const float* ln1_b  = (const float*)d_in[7];
  const float* ln2_g  = (const float*)d_in[8];
  const float* ln2_b  = (const float*)d_in[9];
  const float* tmk    = (const float*)d_in[10];
  const float* tmv    = (const float*)d_in[11];
  const float* tmr    = (const float*)d_in[12];
  const float* tm_kw  = (const float*)d_in[13];
  const float* tm_vw  = (const float*)d_in[14];
  const float* tm_rw  = (const float*)d_in[15];
  const float* tdec   = (const float*)d_in[16];
  const float* tfirst = (const float*)d_in[17];
  const float* out_w  = (const float*)d_in[18];
  const float* cmk    = (const float*)d_in[19];
  const float* cmr    = (const float*)d_in[20];
  const float* cm_kw  = (const float*)d_in[21];
  const float* cm_vw  = (const float*)d_in[22];
  const float* cm_rw  = (const float*)d_in[23];

  float* out   = (float*)d_out;
  float* o_x   = out;
  float* o_h2l = out + (size_t)M_ * D_;
  float* o_hl  = o_h2l + B_ * D_;
  float* o_num = o_hl + B_ * D_;
  float* o_den = o_num + B_ * D_;
  float* o_q   = o_den + B_ * D_;

  char* W = (char*)d_ws;
  const size_t MB = 1024 * 1024;
  ushort_t* w_tmk = (ushort_t*)(W + 0 * MB);
  ushort_t* w_tmv = (ushort_t*)(W + 2 * MB);
  ushort_t* w_tmr = (ushort_t*)(W + 4 * MB);
  ushort_t* w_out = (ushort_t*)(W + 6 * MB);
  ushort_t* w_cmk = (ushort_t*)(W + 8 * MB);
  ushort_t* w_cmv = (ushort_t*)(W + 16 * MB);
  ushort_t* w_cmr = (ushort_t*)(W + 24 * MB);
  float*    hbuf  = (float*)(W + 26 * MB);
  ushort_t* xk    = (ushort_t*)(W + 58 * MB);
  ushort_t* xv    = (ushort_t*)(W + 74 * MB);
  ushort_t* xr    = (ushort_t*)(W + 90 * MB);
  float*    kbuf  = (float*)(W + 106 * MB);
  float*    vbuf  = (float*)(W + 138 * MB);
  float*    rbuf  = (float*)(W + 170 * MB);
  ushort_t* rwkv  = xr;               // reuse (xr dead after r-GEMM)
  ushort_t* xk2   = xk;               // reuse
  ushort_t* xr2   = xv;               // reuse
  ushort_t* kk    = (ushort_t*)kbuf;  // 64MB spans k+v slots
  float*    kv    = rbuf;             // reuse

  dim3 tb(32, 8);
  // weight convert + transpose (bf16, [N][K])
  tconv<<<dim3(D_/32, D_/32), tb, 0, stream>>>(tm_kw, w_tmk, D_, D_);
  tconv<<<dim3(D_/32, D_/32), tb, 0, stream>>>(tm_vw, w_tmv, D_, D_);
  tconv<<<dim3(D_/32, D_/32), tb, 0, stream>>>(tm_rw, w_tmr, D_, D_);
  tconv<<<dim3(D_/32, D_/32), tb, 0, stream>>>(out_w, w_out, D_, D_);
  tconv<<<dim3(F_/32, D_/32), tb, 0, stream>>>(cm_kw, w_cmk, D_, F_);
  tconv<<<dim3(D_/32, F_/32), tb, 0, stream>>>(cm_vw, w_cmv, F_, D_);
  tconv<<<dim3(D_/32, D_/32), tb, 0, stream>>>(cm_rw, w_cmr, D_, D_);

  // time-mix path
  ln_fwd<<<M_, 256, 0, stream>>>(x, ln1_g, ln1_b, hbuf, o_hl);
  mix_tm<<<(M_ * D_ / 4) / 256, 256, 0, stream>>>(hbuf, s_tm, tmk, tmv, tmr, xk, xv, xr);
  gemm128<0><<<dim3(M_/128, D_/128), 256, 0, stream>>>(xk, w_tmk, D_, D_, kbuf, nullptr, nullptr, nullptr);
  gemm128<0><<<dim3(M_/128, D_/128), 256, 0, stream>>>(xv, w_tmv, D_, D_, vbuf, nullptr, nullptr, nullptr);
  gemm128<1><<<dim3(M_/128, D_/128), 256, 0, stream>>>(xr, w_tmr, D_, D_, rbuf, nullptr, nullptr, nullptr);
  wkv_scan<<<(B_ * D_) / 256, 256, 0, stream>>>(kbuf, vbuf, rbuf, s_num, s_den, s_q,
                                                tdec, tfirst, rwkv, o_num, o_den, o_q);
  gemm128<2><<<dim3(M_/128, D_/128), 256, 0, stream>>>(rwkv, w_out, D_, D_, o_x, nullptr, x, nullptr);

  // channel-mix path
  ln_fwd<<<M_, 256, 0, stream>>>(o_x, ln2_g, ln2_b, hbuf, o_h2l);
  mix_cm<<<(M_ * D_ / 4) / 256, 256, 0, stream>>>(hbuf, s_cm, cmk, cmr, xk2, xr2);
  gemm128<3><<<dim3(M_/128, F_/128), 256, 0, stream>>>(xk2, w_cmk, F_, D_, nullptr, kk, nullptr, nullptr);
  gemm128<0><<<dim3(M_/128, D_/128), 256, 0, stream>>>(kk, w_cmv, D_, F_, kv, nullptr, nullptr, nullptr);
  gemm128<4><<<dim3(M_/128, D_/128), 256, 0, stream>>>(xr2, w_cmr, D_, D_, o_x, nullptr, kv, o_x);
}

// Round 2
// 511.575 us; speedup vs baseline: 1.4363x; 1.4363x over previous
//
#include <hip/hip_runtime.h>

typedef unsigned short ushort_t;
typedef __attribute__((ext_vector_type(8))) short short8;
typedef __attribute__((ext_vector_type(4))) float f32x4;

#define B_ 4
#define T_ 2048
#define D_ 1024
#define F_ 4096
#define M_ (B_*T_)
#define CH_ 64
#define NC_ (T_/CH_)   // 32 chunks

#define AS1 __attribute__((address_space(1)))
#define AS3 __attribute__((address_space(3)))

__device__ __forceinline__ ushort_t f2bf(float f) {
  union { float f; unsigned u; } a; a.f = f;
  unsigned r = a.u + 0x7FFFu + ((a.u >> 16) & 1u);
  return (ushort_t)(r >> 16);
}

__device__ __forceinline__ void gl_lds16(const void* g, void* l) {
  __builtin_amdgcn_global_load_lds((AS1 void*)(__UINTPTR_TYPE__)g,
                                   (AS3 void*)l, 16, 0, 0);
}

// ---------------- transpose + f32->bf16 convert: Wt[n][k] = W[k][n] ----------------
__global__ __launch_bounds__(256) void tconv(const float* __restrict__ W,
                                             ushort_t* __restrict__ Wt,
                                             int K, int N) {
  __shared__ float tile[32][33];
  int tx = threadIdx.x, ty = threadIdx.y;
  int n0 = blockIdx.x * 32, k0 = blockIdx.y * 32;
  #pragma unroll
  for (int i = 0; i < 32; i += 8)
    tile[ty + i][tx] = W[(size_t)(k0 + ty + i) * N + n0 + tx];
  __syncthreads();
  #pragma unroll
  for (int i = 0; i < 32; i += 8)
    Wt[(size_t)(n0 + ty + i) * K + k0 + tx] = f2bf(tile[tx][ty + i]);
}

// ---------------- LayerNorm (one block per row of 1024) ----------------
__global__ __launch_bounds__(256) void ln_fwd(const float* __restrict__ x,
                                              const float* __restrict__ g,
                                              const float* __restrict__ bb,
                                              float* __restrict__ h,
                                              float* __restrict__ last) {
  int row = blockIdx.x;
  int tid = threadIdx.x;
  float4 v = ((const float4*)(x + (size_t)row * D_))[tid];
  float s1 = v.x + v.y + v.z + v.w;
  float s2 = v.x * v.x + v.y * v.y + v.z * v.z + v.w * v.w;
  #pragma unroll
  for (int o = 32; o > 0; o >>= 1) { s1 += __shfl_down(s1, o); s2 += __shfl_down(s2, o); }
  __shared__ float r1[4], r2[4];
  if ((tid & 63) == 0) { r1[tid >> 6] = s1; r2[tid >> 6] = s2; }
  __syncthreads();
  s1 = r1[0] + r1[1] + r1[2] + r1[3];
  s2 = r2[0] + r2[1] + r2[2] + r2[3];
  float mu = s1 * (1.0f / D_);
  float rs = rsqrtf(s2 * (1.0f / D_) - mu * mu + 1e-3f);
  float4 gv = ((const float4*)g)[tid];
  float4 bv = ((const float4*)bb)[tid];
  float4 o4;
  o4.x = (v.x - mu) * rs * gv.x + bv.x;
  o4.y = (v.y - mu) * rs * gv.y + bv.y;
  o4.z = (v.z - mu) * rs * gv.z + bv.z;
  o4.w = (v.w - mu) * rs * gv.w + bv.w;
  ((float4*)(h + (size_t)row * D_))[tid] = o4;
  if ((row & (T_ - 1)) == T_ - 1)
    ((float4*)(last + (size_t)(row >> 11) * D_))[tid] = o4;
}

// ---------------- token-shift mixes (f32 in, bf16 out) ----------------
#define MIX1(c, p, f) f2bf((c) * (f) + (p) * (1.0f - (f)))

__global__ __launch_bounds__(256) void mix_tm(const float* __restrict__ h,
                                              const float* __restrict__ st,
                                              const float* __restrict__ mk,
                                              const float* __restrict__ mv,
                                              const float* __restrict__ mr,
                                              ushort_t* __restrict__ xk,
                                              ushort_t* __restrict__ xv,
                                              ushort_t* __restrict__ xr) {
  size_t qi = (size_t)blockIdx.x * 256 + threadIdx.x;  // float4 index
  int dq = (int)(qi & 255);
  size_t td = qi >> 8;
  int t = (int)(td & (T_ - 1));
  int b = (int)(td >> 11);
  float4 hc = ((const float4*)h)[qi];
  float4 hp = (t == 0) ? ((const float4*)st)[b * 256 + dq] : ((const float4*)h)[qi - 256];
  float4 k4 = ((const float4*)mk)[dq];
  float4 v4 = ((const float4*)mv)[dq];
  float4 r4 = ((const float4*)mr)[dq];
  ushort4 ok, ov, orr;
  ok.x = MIX1(hc.x, hp.x, k4.x); ok.y = MIX1(hc.y, hp.y, k4.y);
  ok.z = MIX1(hc.z, hp.z, k4.z); ok.w = MIX1(hc.w, hp.w, k4.w);
  ov.x = MIX1(hc.x, hp.x, v4.x); ov.y = MIX1(hc.y, hp.y, v4.y);
  ov.z = MIX1(hc.z, hp.z, v4.z); ov.w = MIX1(hc.w, hp.w, v4.w);
  orr.x = MIX1(hc.x, hp.x, r4.x); orr.y = MIX1(hc.y, hp.y, r4.y);
  orr.z = MIX1(hc.z, hp.z, r4.z); orr.w = MIX1(hc.w, hp.w, r4.w);
  ((ushort4*)xk)[qi] = ok;
  ((ushort4*)xv)[qi] = ov;
  ((ushort4*)xr)[qi] = orr;
}

__global__ __launch_bounds__(256) void mix_cm(const float* __restrict__ h,
                                              const float* __restrict__ st,
                                              const float* __restrict__ mk,
                                              const float* __restrict__ mr,
                                              ushort_t* __restrict__ xk,
                                              ushort_t* __restrict__ xr) {
  size_t qi = (size_t)blockIdx.x * 256 + threadIdx.x;
  int dq = (int)(qi & 255);
  size_t td = qi >> 8;
  int t = (int)(td & (T_ - 1));
  int b = (int)(td >> 11);
  float4 hc = ((const float4*)h)[qi];
  float4 hp = (t == 0) ? ((const float4*)st)[b * 256 + dq] : ((const float4*)h)[qi - 256];
  float4 k4 = ((const float4*)mk)[dq];
  float4 r4 = ((const float4*)mr)[dq];
  ushort4 ok, orr;
  ok.x = MIX1(hc.x, hp.x, k4.x); ok.y = MIX1(hc.y, hp.y, k4.y);
  ok.z = MIX1(hc.z, hp.z, k4.z); ok.w = MIX1(hc.w, hp.w, k4.w);
  orr.x = MIX1(hc.x, hp.x, r4.x); orr.y = MIX1(hc.y, hp.y, r4.y);
  orr.z = MIX1(hc.z, hp.z, r4.z); orr.w = MIX1(hc.w, hp.w, r4.w);
  ((ushort4*)xk)[qi] = ok;
  ((ushort4*)xr)[qi] = orr;
}

// ---------------- WKV chunked parallel scan ----------------
// Layout for chunk arrays: idx = ((c*B_) + b)*D_ + d
// part1: per-chunk local scan summary (num,den,q) starting from q=-1e30
__global__ __launch_bounds__(256) void wkv_part1(const float* __restrict__ k,
                                                 const float* __restrict__ v,
                                                 const float* __restrict__ tdec,
                                                 float* __restrict__ cn,
                                                 float* __restrict__ cd,
                                                 float* __restrict__ cq) {
  int idx = blockIdx.x * 256 + threadIdx.x;      // [c][b][d]
  int d = idx & (D_ - 1);
  int b = (idx >> 10) & (B_ - 1);
  int c = idx >> 12;
  float w = -__expf(tdec[d]);
  const float* kp = k + ((size_t)b * T_ + c * CH_) * D_ + d;
  const float* vp = v + ((size_t)b * T_ + c * CH_) * D_ + d;
  float num = 0.0f, den = 0.0f, q = -1e30f;
  for (int t0 = 0; t0 < CH_; t0 += 8) {
    float kt[8], vt[8];
    #pragma unroll
    for (int i = 0; i < 8; ++i) {
      size_t off = (size_t)(t0 + i) * D_;
      kt[i] = kp[off]; vt[i] = vp[off];
    }
    #pragma unroll
    for (int i = 0; i < 8; ++i) {
      float kk = kt[i];
      float ms = fmaxf(q + w, kk);
      float e1 = __expf(q + w - ms), e2 = __expf(kk - ms);
      num = e1 * num + e2 * vt[i];
      den = e1 * den + e2;
      q = ms;
    }
  }
  cn[idx] = num; cd[idx] = den; cq[idx] = q;
}

// part2: sequential prefix over 32 chunk summaries; writes exclusive prefixes
// and the final state (num, den, q) outputs.
__global__ __launch_bounds__(256) void wkv_part2(const float* __restrict__ cn,
                                                 const float* __restrict__ cd,
                                                 const float* __restrict__ cq,
                                                 const float* __restrict__ sn,
                                                 const float* __restrict__ sd,
                                                 const float* __restrict__ sq,
                                                 const float* __restrict__ tdec,
                                                 float* __restrict__ pn,
                                                 float* __restrict__ pd,
                                                 float* __restrict__ pq,
                                                 float* __restrict__ on,
                                                 float* __restrict__ od,
                                                 float* __restrict__ oq) {
  int idx = blockIdx.x * 256 + threadIdx.x;      // [b][d], 4096 threads
  int d = idx & (D_ - 1);
  float w = -__expf(tdec[d]);
  float wL = w * (float)CH_;
  float num = sn[idx], den = sd[idx], q = sq[idx];
  #pragma unroll 4
  for (int c = 0; c < NC_; ++c) {
    int j = (c << 12) + idx;
    pn[j] = num; pd[j] = den; pq[j] = q;        // exclusive prefix
    float m2 = cq[j];
    float qn = fmaxf(q + wL, m2);
    float e1 = __expf(q + wL - qn), e2 = __expf(m2 - qn);
    num = e1 * num + e2 * cn[j];
    den = e1 * den + e2 * cd[j];
    q = qn;
  }
  on[idx] = num; od[idx] = den; oq[idx] = q;
}

// part3: replay each chunk from its prefix state, emit r*wkv outputs (bf16)
__global__ __launch_bounds__(256) void wkv_part3(const float* __restrict__ k,
                                                 const float* __restrict__ v,
                                                 const float* __restrict__ r,
                                                 const float* __restrict__ pn,
                                                 const float* __restrict__ pd,
                                                 const float* __restrict__ pq,
                                                 const float* __restrict__ tdec,
                                                 const float* __restrict__ tfirst,
                                                 ushort_t* __restrict__ rwkv) {
  int idx = blockIdx.x * 256 + threadIdx.x;      // [c][b][d]
  int d = idx & (D_ - 1);
  int b = (idx >> 10) & (B_ - 1);
  int c = idx >> 12;
  float w = -__expf(tdec[d]);
  float tf = tfirst[d];
  float num = pn[idx], den = pd[idx], q = pq[idx];
  size_t base = ((size_t)b * T_ + c * CH_) * D_ + d;
  const float* kp = k + base;
  const float* vp = v + base;
  const float* rp = r + base;
  ushort_t* op = rwkv + base;
  for (int t0 = 0; t0 < CH_; t0 += 8) {
    float kt[8], vt[8], rt[8];
    #pragma unroll
    for (int i = 0; i < 8; ++i) {
      size_t off = (size_t)(t0 + i) * D_;
      kt[i] = kp[off]; vt[i] = vp[off]; rt[i] = rp[off];
    }
    #pragma unroll
    for (int i = 0; i < 8; ++i) {
      float kk = kt[i];
      float mo = fmaxf(q, kk + tf);
      float e1 = __expf(q - mo), e2 = __expf(kk + tf - mo);
      float o = (e1 * num + e2 * vt[i]) / (e1 * den + e2);
      op[(size_t)(t0 + i) * D_] = f2bf(rt[i] * o);
      float ms = fmaxf(q + w, kk);
      float e1s = __expf(q + w - ms), e2s = __expf(kk - ms);
      num = e1s * num + e2s * vt[i];
      den = e1s * den + e2s;
      q = ms;
    }
  }
}

// ---------------- 128x128 bf16 MFMA GEMM, B pre-transposed [N][K] ----------------
// EPI: 0 = f32 store, 1 = sigmoid f32, 2 = X + acc (f32), 3 = relu(acc)^2 -> bf16,
//      4 = X2 + sigmoid(acc)*X (f32, in-place capable)
template <int EPI>
__global__ __launch_bounds__(256)
void gemm128(const ushort_t* __restrict__ A, const ushort_t* __restrict__ Bt,
             int N, int K,
             float* __restrict__ Cf, ushort_t* __restrict__ Cb,
             const float* __restrict__ X, const float* __restrict__ X2) {
  __shared__ alignas(16) ushort_t sA[128 * 64];
  __shared__ alignas(16) ushort_t sB[128 * 64];
  const int tid = threadIdx.x;
  const int m0 = blockIdx.x * 128, n0 = blockIdx.y * 128;
  const int lane = tid & 63, wave = tid >> 6;
  const int wm = (wave >> 1) * 64, wn = (wave & 1) * 64;
  const int lr = lane & 15;
  const int lk = (lane >> 4) * 8;

  const ushort_t* ga = A + (size_t)(m0 + (tid >> 3)) * K + (tid & 7) * 8;
  const ushort_t* gb = Bt + (size_t)(n0 + (tid >> 3)) * K + (tid & 7) * 8;
  ushort_t* la = sA + tid * 8;
  ushort_t* lb = sB + tid * 8;

  f32x4 acc[4][4] = {};

  const int ksteps = K >> 6;
  for (int kt = 0; kt < ksteps; ++kt) {
    const int kof = kt * 64;
    #pragma unroll
    for (int i = 0; i < 4; ++i) {
      gl_lds16(ga + (size_t)(i * 32) * K + kof, la + i * 2048);
      gl_lds16(gb + (size_t)(i * 32) * K + kof, lb + i * 2048);
    }
    __syncthreads();
    short8 af[2][4], bfr[2][4];
    #pragma unroll
    for (int s = 0; s < 2; ++s)
      #pragma unroll
      for (int i = 0; i < 4; ++i) {
        af[s][i]  = *(const short8*)&sA[(wm + i * 16 + lr) * 64 + s * 32 + lk];
        bfr[s][i] = *(const short8*)&sB[(wn + i * 16 + lr) * 64 + s * 32 + lk];
      }
    #pragma unroll
    for (int s = 0; s < 2; ++s)
      #pragma unroll
      for (int mi = 0; mi < 4; ++mi)
        #pragma unroll
        for (int ni = 0; ni < 4; ++ni)
          acc[mi][ni] = __builtin_amdgcn_mfma_f32_16x16x32_bf16(
              af[s][mi], bfr[s][ni], acc[mi][ni], 0, 0, 0);
    __syncthreads();
  }

  #pragma unroll
  for (int mi = 0; mi < 4; ++mi)
    #pragma unroll
    for (int ni = 0; ni < 4; ++ni)
      #pragma unroll
      for (int j = 0; j < 4; ++j) {
        int row = m0 + wm + mi * 16 + ((lane >> 4) << 2) + j;
        int col = n0 + wn + ni * 16 + lr;
        size_t idx = (size_t)row * N + col;
        float v = acc[mi][ni][j];
        if (EPI == 0) {
          Cf[idx] = v;
        } else if (EPI == 1) {
          Cf[idx] = 1.0f / (1.0f + __expf(-v));
        } else if (EPI == 2) {
          Cf[idx] = X[idx] + v;
        } else if (EPI == 3) {
          float t = v > 0.0f ? v : 0.0f;
          Cb[idx] = f2bf(t * t);
        } else if (EPI == 4) {
          float s = 1.0f / (1.0f + __expf(-v));
          Cf[idx] = X2[idx] + s * X[idx];
        }
      }
}

// ---------------- launcher ----------------
extern "C" void kernel_launch(void* const* d_in, const int* in_sizes, int n_in,
                              void* d_out, int out_size, void* d_ws, size_t ws_size,
                              hipStream_t stream) {
  const float* x      = (const float*)d_in[0];
  const float* s_cm   = (const float*)d_in[1];
  const float* s_tm   = (const float*)d_in[2];
  const float* s_num  = (const float*)d_in[3];
  const float* s_den  = (const float*)d_in[4];
  const float* s_q    = (const float*)d_in[5];
  const float* ln1_g  = (const float*)d_in[6];
  const float* ln1_b  = (const float*)d_in[7];
  const float* ln2_g  = (const float*)d_in[8];
  const float* ln2_b  = (const float*)d_in[9];
  const float* tmk    = (const float*)d_in[10];
  const float* tmv    = (const float*)d_in[11];
  const float* tmr    = (const float*)d_in[12];
  const float* tm_kw  = (const float*)d_in[13];
  const float* tm_vw  = (const float*)d_in[14];
  const float* tm_rw  = (const float*)d_in[15];
  const float* tdec   = (const float*)d_in[16];
  const float* tfirst = (const float*)d_in[17];
  const float* out_w  = (const float*)d_in[18];
  const float* cmk    = (const float*)d_in[19];
  const float* cmr    = (const float*)d_in[20];
  const float* cm_kw  = (const float*)d_in[21];
  const float* cm_vw  = (const float*)d_in[22];
  const float* cm_rw  = (const float*)d_in[23];

  float* out   = (float*)d_out;
  float* o_x   = out;
  float* o_h2l = out + (size_t)M_ * D_;
  float* o_hl  = o_h2l + B_ * D_;
  float* o_num = o_hl + B_ * D_;
  float* o_den = o_num + B_ * D_;
  float* o_q   = o_den + B_ * D_;

  char* W = (char*)d_ws;
  const size_t MB = 1024 * 1024;
  ushort_t* w_tmk = (ushort_t*)(W + 0 * MB);
  ushort_t* w_tmv = (ushort_t*)(W + 2 * MB);
  ushort_t* w_tmr = (ushort_t*)(W + 4 * MB);
  ushort_t* w_out = (ushort_t*)(W + 6 * MB);
  ushort_t* w_cmk = (ushort_t*)(W + 8 * MB);
  ushort_t* w_cmv = (ushort_t*)(W + 16 * MB);
  ushort_t* w_cmr = (ushort_t*)(W + 24 * MB);
  float*    hbuf  = (float*)(W + 26 * MB);
  ushort_t* xk    = (ushort_t*)(W + 58 * MB);
  ushort_t* xv    = (ushort_t*)(W + 74 * MB);
  ushort_t* xr    = (ushort_t*)(W + 90 * MB);
  float*    kbuf  = (float*)(W + 106 * MB);
  float*    vbuf  = (float*)(W + 138 * MB);
  float*    rbuf  = (float*)(W + 170 * MB);
  ushort_t* rwkv  = xr;               // reuse (xr dead after r-GEMM)
  ushort_t* xk2   = xk;               // reuse
  ushort_t* xr2   = xv;               // reuse
  ushort_t* kk    = (ushort_t*)kbuf;  // 64MB spans k+v slots
  float*    kv    = rbuf;             // reuse

  // scan scratch: reuse hbuf region (dead between mix_tm and ln_fwd#2)
  // 6 arrays of NC_*B_*D_ floats (512 KB each)
  float* cn = (float*)(W + 26 * MB + 0 * 512 * 1024);
  float* cd = (float*)(W + 26 * MB + 1 * 512 * 1024);
  float* cq = (float*)(W + 26 * MB + 2 * 512 * 1024);
  float* pn = (float*)(W + 26 * MB + 3 * 512 * 1024);
  float* pd = (float*)(W + 26 * MB + 4 * 512 * 1024);
  float* pq = (float*)(W + 26 * MB + 5 * 512 * 1024);

  dim3 tb(32, 8);
  // weight convert + transpose (bf16, [N][K])
  tconv<<<dim3(D_/32, D_/32), tb, 0, stream>>>(tm_kw, w_tmk, D_, D_);
  tconv<<<dim3(D_/32, D_/32), tb, 0, stream>>>(tm_vw, w_tmv, D_, D_);
  tconv<<<dim3(D_/32, D_/32), tb, 0, stream>>>(tm_rw, w_tmr, D_, D_);
  tconv<<<dim3(D_/32, D_/32), tb, 0, stream>>>(out_w, w_out, D_, D_);
  tconv<<<dim3(F_/32, D_/32), tb, 0, stream>>>(cm_kw, w_cmk, D_, F_);
  tconv<<<dim3(D_/32, F_/32), tb, 0, stream>>>(cm_vw, w_cmv, F_, D_);
  tconv<<<dim3(D_/32, D_/32), tb, 0, stream>>>(cm_rw, w_cmr, D_, D_);

  // time-mix path
  ln_fwd<<<M_, 256, 0, stream>>>(x, ln1_g, ln1_b, hbuf, o_hl);
  mix_tm<<<(M_ * D_ / 4) / 256, 256, 0, stream>>>(hbuf, s_tm, tmk, tmv, tmr, xk, xv, xr);
  gemm128<0><<<dim3(M_/128, D_/128), 256, 0, stream>>>(xk, w_tmk, D_, D_, kbuf, nullptr, nullptr, nullptr);
  gemm128<0><<<dim3(M_/128, D_/128), 256, 0, stream>>>(xv, w_tmv, D_, D_, vbuf, nullptr, nullptr, nullptr);
  gemm128<1><<<dim3(M_/128, D_/128), 256, 0, stream>>>(xr, w_tmr, D_, D_, rbuf, nullptr, nullptr, nullptr);

  // chunked parallel WKV scan
  wkv_part1<<<(NC_ * B_ * D_) / 256, 256, 0, stream>>>(kbuf, vbuf, tdec, cn, cd, cq);
  wkv_part2<<<(B_ * D_) / 256, 256, 0, stream>>>(cn, cd, cq, s_num, s_den, s_q, tdec,
                                                 pn, pd, pq, o_num, o_den, o_q);
  wkv_part3<<<(NC_ * B_ * D_) / 256, 256, 0, stream>>>(kbuf, vbuf, rbuf, pn, pd, pq,
                                                       tdec, tfirst, rwkv);

  gemm128<2><<<dim3(M_/128, D_/128), 256, 0, stream>>>(rwkv, w_out, D_, D_, o_x, nullptr, x, nullptr);

  // channel-mix path
  ln_fwd<<<M_, 256, 0, stream>>>(o_x, ln2_g, ln2_b, hbuf, o_h2l);
  mix_cm<<<(M_ * D_ / 4) / 256, 256, 0, stream>>>(hbuf, s_cm, cmk, cmr, xk2, xr2);
  gemm128<3><<<dim3(M_/128, F_/128), 256, 0, stream>>>(xk2, w_cmk, F_, D_, nullptr, kk, nullptr, nullptr);
  gemm128<0><<<dim3(M_/128, D_/128), 256, 0, stream>>>(kk, w_cmv, D_, F_, kv, nullptr, nullptr, nullptr);
  gemm128<4><<<dim3(M_/128, D_/128), 256, 0, stream>>>(xr2, w_cmr, D_, D_, o_x, nullptr, kv, o_x);
}

// Round 3
// 449.961 us; speedup vs baseline: 1.6330x; 1.1369x over previous
//
#include <hip/hip_runtime.h>

typedef unsigned short ushort_t;
typedef __attribute__((ext_vector_type(8))) short short8;
typedef __attribute__((ext_vector_type(4))) float f32x4;

#define B_ 4
#define T_ 2048
#define D_ 1024
#define F_ 4096
#define M_ (B_*T_)
#define CH_ 64
#define NC_ (T_/CH_)   // 32 chunks

#define AS1 __attribute__((address_space(1)))
#define AS3 __attribute__((address_space(3)))

__device__ __forceinline__ ushort_t f2bf(float f) {
  union { float f; unsigned u; } a; a.f = f;
  unsigned r = a.u + 0x7FFFu + ((a.u >> 16) & 1u);
  return (ushort_t)(r >> 16);
}

__device__ __forceinline__ void gl_lds16(const void* g, void* l) {
  __builtin_amdgcn_global_load_lds((AS1 void*)(__UINTPTR_TYPE__)g,
                                   (AS3 void*)l, 16, 0, 0);
}

// ---------------- transpose + f32->bf16 convert: Wt[n][k] = W[k][n] ----------------
__global__ __launch_bounds__(256) void tconv(const float* __restrict__ W,
                                             ushort_t* __restrict__ Wt,
                                             int K, int N) {
  __shared__ float tile[32][33];
  int tx = threadIdx.x, ty = threadIdx.y;
  int n0 = blockIdx.x * 32, k0 = blockIdx.y * 32;
  #pragma unroll
  for (int i = 0; i < 32; i += 8)
    tile[ty + i][tx] = W[(size_t)(k0 + ty + i) * N + n0 + tx];
  __syncthreads();
  #pragma unroll
  for (int i = 0; i < 32; i += 8)
    Wt[(size_t)(n0 + ty + i) * K + k0 + tx] = f2bf(tile[tx][ty + i]);
}

// ---------------- LayerNorm (one block per row of 1024) ----------------
__global__ __launch_bounds__(256) void ln_fwd(const float* __restrict__ x,
                                              const float* __restrict__ g,
                                              const float* __restrict__ bb,
                                              float* __restrict__ h,
                                              float* __restrict__ last) {
  int row = blockIdx.x;
  int tid = threadIdx.x;
  float4 v = ((const float4*)(x + (size_t)row * D_))[tid];
  float s1 = v.x + v.y + v.z + v.w;
  float s2 = v.x * v.x + v.y * v.y + v.z * v.z + v.w * v.w;
  #pragma unroll
  for (int o = 32; o > 0; o >>= 1) { s1 += __shfl_down(s1, o); s2 += __shfl_down(s2, o); }
  __shared__ float r1[4], r2[4];
  if ((tid & 63) == 0) { r1[tid >> 6] = s1; r2[tid >> 6] = s2; }
  __syncthreads();
  s1 = r1[0] + r1[1] + r1[2] + r1[3];
  s2 = r2[0] + r2[1] + r2[2] + r2[3];
  float mu = s1 * (1.0f / D_);
  float rs = rsqrtf(s2 * (1.0f / D_) - mu * mu + 1e-3f);
  float4 gv = ((const float4*)g)[tid];
  float4 bv = ((const float4*)bb)[tid];
  float4 o4;
  o4.x = (v.x - mu) * rs * gv.x + bv.x;
  o4.y = (v.y - mu) * rs * gv.y + bv.y;
  o4.z = (v.z - mu) * rs * gv.z + bv.z;
  o4.w = (v.w - mu) * rs * gv.w + bv.w;
  ((float4*)(h + (size_t)row * D_))[tid] = o4;
  if ((row & (T_ - 1)) == T_ - 1)
    ((float4*)(last + (size_t)(row >> 11) * D_))[tid] = o4;
}

// ---------------- token-shift mixes (f32 in, bf16 out) ----------------
#define MIX1(c, p, f) f2bf((c) * (f) + (p) * (1.0f - (f)))

__global__ __launch_bounds__(256) void mix_tm(const float* __restrict__ h,
                                              const float* __restrict__ st,
                                              const float* __restrict__ mk,
                                              const float* __restrict__ mv,
                                              const float* __restrict__ mr,
                                              ushort_t* __restrict__ xk,
                                              ushort_t* __restrict__ xv,
                                              ushort_t* __restrict__ xr) {
  size_t qi = (size_t)blockIdx.x * 256 + threadIdx.x;  // float4 index
  int dq = (int)(qi & 255);
  size_t td = qi >> 8;
  int t = (int)(td & (T_ - 1));
  int b = (int)(td >> 11);
  float4 hc = ((const float4*)h)[qi];
  float4 hp = (t == 0) ? ((const float4*)st)[b * 256 + dq] : ((const float4*)h)[qi - 256];
  float4 k4 = ((const float4*)mk)[dq];
  float4 v4 = ((const float4*)mv)[dq];
  float4 r4 = ((const float4*)mr)[dq];
  ushort4 ok, ov, orr;
  ok.x = MIX1(hc.x, hp.x, k4.x); ok.y = MIX1(hc.y, hp.y, k4.y);
  ok.z = MIX1(hc.z, hp.z, k4.z); ok.w = MIX1(hc.w, hp.w, k4.w);
  ov.x = MIX1(hc.x, hp.x, v4.x); ov.y = MIX1(hc.y, hp.y, v4.y);
  ov.z = MIX1(hc.z, hp.z, v4.z); ov.w = MIX1(hc.w, hp.w, v4.w);
  orr.x = MIX1(hc.x, hp.x, r4.x); orr.y = MIX1(hc.y, hp.y, r4.y);
  orr.z = MIX1(hc.z, hp.z, r4.z); orr.w = MIX1(hc.w, hp.w, r4.w);
  ((ushort4*)xk)[qi] = ok;
  ((ushort4*)xv)[qi] = ov;
  ((ushort4*)xr)[qi] = orr;
}

__global__ __launch_bounds__(256) void mix_cm(const float* __restrict__ h,
                                              const float* __restrict__ st,
                                              const float* __restrict__ mk,
                                              const float* __restrict__ mr,
                                              ushort_t* __restrict__ xk,
                                              ushort_t* __restrict__ xr) {
  size_t qi = (size_t)blockIdx.x * 256 + threadIdx.x;
  int dq = (int)(qi & 255);
  size_t td = qi >> 8;
  int t = (int)(td & (T_ - 1));
  int b = (int)(td >> 11);
  float4 hc = ((const float4*)h)[qi];
  float4 hp = (t == 0) ? ((const float4*)st)[b * 256 + dq] : ((const float4*)h)[qi - 256];
  float4 k4 = ((const float4*)mk)[dq];
  float4 r4 = ((const float4*)mr)[dq];
  ushort4 ok, orr;
  ok.x = MIX1(hc.x, hp.x, k4.x); ok.y = MIX1(hc.y, hp.y, k4.y);
  ok.z = MIX1(hc.z, hp.z, k4.z); ok.w = MIX1(hc.w, hp.w, k4.w);
  orr.x = MIX1(hc.x, hp.x, r4.x); orr.y = MIX1(hc.y, hp.y, r4.y);
  orr.z = MIX1(hc.z, hp.z, r4.z); orr.w = MIX1(hc.w, hp.w, r4.w);
  ((ushort4*)xk)[qi] = ok;
  ((ushort4*)xr)[qi] = orr;
}

// ---------------- WKV chunked parallel scan ----------------
__global__ __launch_bounds__(256) void wkv_part1(const float* __restrict__ k,
                                                 const float* __restrict__ v,
                                                 const float* __restrict__ tdec,
                                                 float* __restrict__ cn,
                                                 float* __restrict__ cd,
                                                 float* __restrict__ cq) {
  int idx = blockIdx.x * 256 + threadIdx.x;      // [c][b][d]
  int d = idx & (D_ - 1);
  int b = (idx >> 10) & (B_ - 1);
  int c = idx >> 12;
  float w = -__expf(tdec[d]);
  const float* kp = k + ((size_t)b * T_ + c * CH_) * D_ + d;
  const float* vp = v + ((size_t)b * T_ + c * CH_) * D_ + d;
  float num = 0.0f, den = 0.0f, q = -1e30f;
  for (int t0 = 0; t0 < CH_; t0 += 8) {
    float kt[8], vt[8];
    #pragma unroll
    for (int i = 0; i < 8; ++i) {
      size_t off = (size_t)(t0 + i) * D_;
      kt[i] = kp[off]; vt[i] = vp[off];
    }
    #pragma unroll
    for (int i = 0; i < 8; ++i) {
      float kk = kt[i];
      float ms = fmaxf(q + w, kk);
      float e1 = __expf(q + w - ms), e2 = __expf(kk - ms);
      num = e1 * num + e2 * vt[i];
      den = e1 * den + e2;
      q = ms;
    }
  }
  cn[idx] = num; cd[idx] = den; cq[idx] = q;
}

__global__ __launch_bounds__(256) void wkv_part2(const float* __restrict__ cn,
                                                 const float* __restrict__ cd,
                                                 const float* __restrict__ cq,
                                                 const float* __restrict__ sn,
                                                 const float* __restrict__ sd,
                                                 const float* __restrict__ sq,
                                                 const float* __restrict__ tdec,
                                                 float* __restrict__ pn,
                                                 float* __restrict__ pd,
                                                 float* __restrict__ pq,
                                                 float* __restrict__ on,
                                                 float* __restrict__ od,
                                                 float* __restrict__ oq) {
  int idx = blockIdx.x * 256 + threadIdx.x;      // [b][d], 4096 threads
  int d = idx & (D_ - 1);
  float w = -__expf(tdec[d]);
  float wL = w * (float)CH_;
  float num = sn[idx], den = sd[idx], q = sq[idx];
  #pragma unroll 4
  for (int c = 0; c < NC_; ++c) {
    int j = (c << 12) + idx;
    pn[j] = num; pd[j] = den; pq[j] = q;        // exclusive prefix
    float m2 = cq[j];
    float qn = fmaxf(q + wL, m2);
    float e1 = __expf(q + wL - qn), e2 = __expf(m2 - qn);
    num = e1 * num + e2 * cn[j];
    den = e1 * den + e2 * cd[j];
    q = qn;
  }
  on[idx] = num; od[idx] = den; oq[idx] = q;
}

__global__ __launch_bounds__(256) void wkv_part3(const float* __restrict__ k,
                                                 const float* __restrict__ v,
                                                 const float* __restrict__ r,
                                                 const float* __restrict__ pn,
                                                 const float* __restrict__ pd,
                                                 const float* __restrict__ pq,
                                                 const float* __restrict__ tdec,
                                                 const float* __restrict__ tfirst,
                                                 ushort_t* __restrict__ rwkv) {
  int idx = blockIdx.x * 256 + threadIdx.x;      // [c][b][d]
  int d = idx & (D_ - 1);
  int b = (idx >> 10) & (B_ - 1);
  int c = idx >> 12;
  float w = -__expf(tdec[d]);
  float tf = tfirst[d];
  float num = pn[idx], den = pd[idx], q = pq[idx];
  size_t base = ((size_t)b * T_ + c * CH_) * D_ + d;
  const float* kp = k + base;
  const float* vp = v + base;
  const float* rp = r + base;
  ushort_t* op = rwkv + base;
  for (int t0 = 0; t0 < CH_; t0 += 8) {
    float kt[8], vt[8], rt[8];
    #pragma unroll
    for (int i = 0; i < 8; ++i) {
      size_t off = (size_t)(t0 + i) * D_;
      kt[i] = kp[off]; vt[i] = vp[off]; rt[i] = rp[off];
    }
    #pragma unroll
    for (int i = 0; i < 8; ++i) {
      float kk = kt[i];
      float mo = fmaxf(q, kk + tf);
      float e1 = __expf(q - mo), e2 = __expf(kk + tf - mo);
      float o = (e1 * num + e2 * vt[i]) / (e1 * den + e2);
      op[(size_t)(t0 + i) * D_] = f2bf(rt[i] * o);
      float ms = fmaxf(q + w, kk);
      float e1s = __expf(q + w - ms), e2s = __expf(kk - ms);
      num = e1s * num + e2s * vt[i];
      den = e1s * den + e2s;
      q = ms;
    }
  }
}

// ---------------- 128x128 bf16 MFMA GEMM (m97 structure), B [N][K] ----------------
// EPI: 0 = f32 store, 1 = sigmoid f32, 2 = X + acc (f32),
//      4 = X2 + sigmoid(acc)*(X+Xb) (f32)
template <int EPI>
__global__ __launch_bounds__(256)
void gemm128(const ushort_t* __restrict__ A, const ushort_t* __restrict__ Bt,
             int N, int K,
             float* __restrict__ Cf, ushort_t* __restrict__ Cb,
             const float* __restrict__ X, const float* __restrict__ X2,
             const float* __restrict__ Xb) {
  __shared__ alignas(16) ushort_t sA[128 * 64];
  __shared__ alignas(16) ushort_t sB[128 * 64];
  const int tid = threadIdx.x;
  const int m0 = blockIdx.x * 128, n0 = blockIdx.y * 128;
  const int lane = tid & 63, wave = tid >> 6;
  const int wm = (wave >> 1) * 64, wn = (wave & 1) * 64;
  const int lr = lane & 15;
  const int lk = (lane >> 4) * 8;

  const ushort_t* ga = A + (size_t)(m0 + (tid >> 3)) * K + (tid & 7) * 8;
  const ushort_t* gb = Bt + (size_t)(n0 + (tid >> 3)) * K + (tid & 7) * 8;
  ushort_t* la = sA + tid * 8;
  ushort_t* lb = sB + tid * 8;

  f32x4 acc[4][4] = {};

  const int ksteps = K >> 6;
  for (int kt = 0; kt < ksteps; ++kt) {
    const int kof = kt * 64;
    #pragma unroll
    for (int i = 0; i < 4; ++i) {
      gl_lds16(ga + (size_t)(i * 32) * K + kof, la + i * 2048);
      gl_lds16(gb + (size_t)(i * 32) * K + kof, lb + i * 2048);
    }
    __syncthreads();
    short8 af[2][4], bfr[2][4];
    #pragma unroll
    for (int s = 0; s < 2; ++s)
      #pragma unroll
      for (int i = 0; i < 4; ++i) {
        af[s][i]  = *(const short8*)&sA[(wm + i * 16 + lr) * 64 + s * 32 + lk];
        bfr[s][i] = *(const short8*)&sB[(wn + i * 16 + lr) * 64 + s * 32 + lk];
      }
    #pragma unroll
    for (int s = 0; s < 2; ++s)
      #pragma unroll
      for (int mi = 0; mi < 4; ++mi)
        #pragma unroll
        for (int ni = 0; ni < 4; ++ni)
          acc[mi][ni] = __builtin_amdgcn_mfma_f32_16x16x32_bf16(
              af[s][mi], bfr[s][ni], acc[mi][ni], 0, 0, 0);
    __syncthreads();
  }

  #pragma unroll
  for (int mi = 0; mi < 4; ++mi)
    #pragma unroll
    for (int ni = 0; ni < 4; ++ni)
      #pragma unroll
      for (int j = 0; j < 4; ++j) {
        int row = m0 + wm + mi * 16 + ((lane >> 4) << 2) + j;
        int col = n0 + wn + ni * 16 + lr;
        size_t idx = (size_t)row * N + col;
        float v = acc[mi][ni][j];
        if (EPI == 0) {
          Cf[idx] = v;
        } else if (EPI == 1) {
          Cf[idx] = 1.0f / (1.0f + __expf(-v));
        } else if (EPI == 2) {
          Cf[idx] = X[idx] + v;
        } else if (EPI == 4) {
          float s = 1.0f / (1.0f + __expf(-v));
          Cf[idx] = X2[idx] + s * (X[idx] + Xb[idx]);
        }
      }
}

// ---------------- 256x256 8-wave pipelined GEMM (T2+T3+T4+T5), B [N][K] ----------
// EPI: 0 = f32 store (split-K aware: blockIdx.z selects Cf/Cf2), 1 = relu^2 -> bf16
template <int EPI>
__global__ __launch_bounds__(512, 2)
void gemm256(const ushort_t* __restrict__ A, const ushort_t* __restrict__ Bt,
             int N, int K, int ktn,
             float* __restrict__ Cf, float* __restrict__ Cf2,
             ushort_t* __restrict__ Cb) {
  __shared__ alignas(16) ushort_t sA[2][256 * 64];
  __shared__ alignas(16) ushort_t sB[2][256 * 64];
  const int tid = threadIdx.x;
  const int lane = tid & 63;
  const int wave = tid >> 6;
  const int wr = wave >> 2, wc = wave & 3;      // 2 x 4 wave grid
  const int l15 = lane & 15;
  const int kb = (lane >> 4) << 4;              // byte offset of k-group
  const int m0 = blockIdx.x * 256, n0 = blockIdx.y * 256;
  const int kt0 = blockIdx.z * ktn;
  const ushort_t* gA = A + (size_t)m0 * K + (size_t)kt0 * 64;
  const ushort_t* gB = Bt + (size_t)n0 * K + (size_t)kt0 * 64;

  // staging coords (swizzled global source, linear LDS dest — rule 21/m173)
  const int sr = tid >> 3;                      // 0..63
  const int sc8 = (tid & 7) ^ (sr & 7);         // pre-swizzled col-8 group
  const int scb = (tid & 7) * 16;               // linear LDS byte col

  // stage half-tile h (0,1 = A halves; 2,3 = B halves) of rel. K-tile kt
  auto stage = [&](int dbuf, int kt, int h) {
    const ushort_t* g = (h < 2) ? gA : gB;
    ushort_t* sb = (h < 2) ? sA[dbuf] : sB[dbuf];
    int rbase = (h & 1) * 128;
    #pragma unroll
    for (int i = 0; i < 2; ++i) {
      int row = rbase + i * 64 + sr;
      gl_lds16(g + (size_t)row * K + (size_t)kt * 64 + sc8 * 8,
               (char*)sb + row * 128 + scb);
    }
  };

  // swizzled fragment read: logical (row, k-sub s5) -> short8
  auto ld = [&](const ushort_t* sbuf, int row, int s5) -> short8 {
    int cb = ((s5 << 6) + kb) ^ ((row & 7) << 4);
    return *(const short8*)((const char*)sbuf + row * 128 + cb);
  };

  f32x4 acc[8][4] = {};

  // prologue: K-tile 0 fully staged (8 loads/wave)
  stage(0, 0, 0); stage(0, 0, 1); stage(0, 0, 2); stage(0, 0, 3);

  for (int t = 0; t < ktn; ++t) {
    const int cur = t & 1, nxt = cur ^ 1;
    const bool more = (t + 1 < ktn);
    // stage A-halves of t+1, then wait for t's 8 loads (4 stay in flight)
    if (more) { stage(nxt, t + 1, 0); stage(nxt, t + 1, 1); }
    if (more) asm volatile("s_waitcnt vmcnt(4)" ::: "memory");
    else      asm volatile("s_waitcnt vmcnt(0)" ::: "memory");
    __builtin_amdgcn_s_barrier();

    const ushort_t* curA = sA[cur];
    const ushort_t* curB = sB[cur];
    short8 bfr[4][2];

#define G256_MFMA16(MI0, A00, A01, A10, A11)                                  \
    __builtin_amdgcn_s_setprio(1);                                            \
    _Pragma("unroll")                                                         \
    for (int ni = 0; ni < 4; ++ni) {                                          \
      acc[MI0][ni] = __builtin_amdgcn_mfma_f32_16x16x32_bf16(                 \
          A00, bfr[ni][0], acc[MI0][ni], 0, 0, 0);                            \
      acc[MI0][ni] = __builtin_amdgcn_mfma_f32_16x16x32_bf16(                 \
          A01, bfr[ni][1], acc[MI0][ni], 0, 0, 0);                            \
      acc[MI0 + 1][ni] = __builtin_amdgcn_mfma_f32_16x16x32_bf16(             \
          A10, bfr[ni][0], acc[MI0 + 1][ni], 0, 0, 0);                        \
      acc[MI0 + 1][ni] = __builtin_amdgcn_mfma_f32_16x16x32_bf16(             \
          A11, bfr[ni][1], acc[MI0 + 1][ni], 0, 0, 0);                        \
    }                                                                         \
    __builtin_amdgcn_s_setprio(0);

#define G256_SYNC_IN()                                                        \
    asm volatile("" ::: "memory");                                            \
    __builtin_amdgcn_s_barrier();                                             \
    asm volatile("s_waitcnt lgkmcnt(0)" ::: "memory");                        \
    __builtin_amdgcn_sched_barrier(0);

#define G256_SYNC_OUT()                                                       \
    asm volatile("" ::: "memory");                                            \
    __builtin_amdgcn_s_barrier();

    {   // ---- phase 0: read all B frags + A(0,1); stage B-half0 of t+1
      #pragma unroll
      for (int ni = 0; ni < 4; ++ni)
        #pragma unroll
        for (int s = 0; s < 2; ++s)
          bfr[ni][s] = ld(curB, wc * 64 + ni * 16 + l15, s);
      short8 a00 = ld(curA, wr * 128 + 0 * 16 + l15, 0);
      short8 a01 = ld(curA, wr * 128 + 0 * 16 + l15, 1);
      short8 a10 = ld(curA, wr * 128 + 1 * 16 + l15, 0);
      short8 a11 = ld(curA, wr * 128 + 1 * 16 + l15, 1);
      if (more) stage(nxt, t + 1, 2);
      G256_SYNC_IN();
      G256_MFMA16(0, a00, a01, a10, a11);
      G256_SYNC_OUT();
    }
    {   // ---- phase 1: A(2,3); stage B-half1 of t+1
      short8 a00 = ld(curA, wr * 128 + 2 * 16 + l15, 0);
      short8 a01 = ld(curA, wr * 128 + 2 * 16 + l15, 1);
      short8 a10 = ld(curA, wr * 128 + 3 * 16 + l15, 0);
      short8 a11 = ld(curA, wr * 128 + 3 * 16 + l15, 1);
      if (more) stage(nxt, t + 1, 3);
      G256_SYNC_IN();
      G256_MFMA16(2, a00, a01, a10, a11);
      G256_SYNC_OUT();
    }
    {   // ---- phase 2: A(4,5)
      short8 a00 = ld(curA, wr * 128 + 4 * 16 + l15, 0);
      short8 a01 = ld(curA, wr * 128 + 4 * 16 + l15, 1);
      short8 a10 = ld(curA, wr * 128 + 5 * 16 + l15, 0);
      short8 a11 = ld(curA, wr * 128 + 5 * 16 + l15, 1);
      G256_SYNC_IN();
      G256_MFMA16(4, a00, a01, a10, a11);
      G256_SYNC_OUT();
    }
    {   // ---- phase 3: A(6,7)
      short8 a00 = ld(curA, wr * 128 + 6 * 16 + l15, 0);
      short8 a01 = ld(curA, wr * 128 + 6 * 16 + l15, 1);
      short8 a10 = ld(curA, wr * 128 + 7 * 16 + l15, 0);
      short8 a11 = ld(curA, wr * 128 + 7 * 16 + l15, 1);
      G256_SYNC_IN();
      G256_MFMA16(6, a00, a01, a10, a11);
      G256_SYNC_OUT();
    }
  }

  float* cfp = Cf;
  if (EPI == 0 && blockIdx.z) cfp = Cf2;
  #pragma unroll
  for (int mi = 0; mi < 8; ++mi)
    #pragma unroll
    for (int ni = 0; ni < 4; ++ni)
      #pragma unroll
      for (int j = 0; j < 4; ++j) {
        int row = m0 + wr * 128 + mi * 16 + ((lane >> 4) << 2) + j;
        int col = n0 + wc * 64 + ni * 16 + l15;
        size_t idx = (size_t)row * N + col;
        float v = acc[mi][ni][j];
        if (EPI == 0) {
          cfp[idx] = v;
        } else {
          float tt = v > 0.0f ? v : 0.0f;
          Cb[idx] = f2bf(tt * tt);
        }
      }
}

// ---------------- launcher ----------------
extern "C" void kernel_launch(void* const* d_in, const int* in_sizes, int n_in,
                              void* d_out, int out_size, void* d_ws, size_t ws_size,
                              hipStream_t stream) {
  const float* x      = (const float*)d_in[0];
  const float* s_cm   = (const float*)d_in[1];
  const float* s_tm   = (const float*)d_in[2];
  const float* s_num  = (const float*)d_in[3];
  const float* s_den  = (const float*)d_in[4];
  const float* s_q    = (const float*)d_in[5];
  const float* ln1_g  = (const float*)d_in[6];
  const float* ln1_b  = (const float*)d_in[7];
  const float* ln2_g  = (const float*)d_in[8];
  const float* ln2_b  = (const float*)d_in[9];
  const float* tmk    = (const float*)d_in[10];
  const float* tmv    = (const float*)d_in[11];
  const float* tmr    = (const float*)d_in[12];
  const float* tm_kw  = (const float*)d_in[13];
  const float* tm_vw  = (const float*)d_in[14];
  const float* tm_rw  = (const float*)d_in[15];
  const float* tdec   = (const float*)d_in[16];
  const float* tfirst = (const float*)d_in[17];
  const float* out_w  = (const float*)d_in[18];
  const float* cmk    = (const float*)d_in[19];
  const float* cmr    = (const float*)d_in[20];
  const float* cm_kw  = (const float*)d_in[21];
  const float* cm_vw  = (const float*)d_in[22];
  const float* cm_rw  = (const float*)d_in[23];

  float* out   = (float*)d_out;
  float* o_x   = out;
  float* o_h2l = out + (size_t)M_ * D_;
  float* o_hl  = o_h2l + B_ * D_;
  float* o_num = o_hl + B_ * D_;
  float* o_den = o_num + B_ * D_;
  float* o_q   = o_den + B_ * D_;

  char* W = (char*)d_ws;
  const size_t MB = 1024 * 1024;
  ushort_t* w_tmk = (ushort_t*)(W + 0 * MB);
  ushort_t* w_tmv = (ushort_t*)(W + 2 * MB);
  ushort_t* w_tmr = (ushort_t*)(W + 4 * MB);
  ushort_t* w_out = (ushort_t*)(W + 6 * MB);
  ushort_t* w_cmk = (ushort_t*)(W + 8 * MB);
  ushort_t* w_cmv = (ushort_t*)(W + 16 * MB);
  ushort_t* w_cmr = (ushort_t*)(W + 24 * MB);
  float*    hbuf  = (float*)(W + 26 * MB);
  ushort_t* xk    = (ushort_t*)(W + 58 * MB);
  ushort_t* xv    = (ushort_t*)(W + 74 * MB);
  ushort_t* xr    = (ushort_t*)(W + 90 * MB);
  float*    kbuf  = (float*)(W + 106 * MB);
  float*    vbuf  = (float*)(W + 138 * MB);
  float*    rbuf  = (float*)(W + 170 * MB);
  ushort_t* rwkv  = xr;               // reuse (xr dead after r-GEMM)
  ushort_t* xk2   = xk;               // reuse
  ushort_t* xr2   = xv;               // reuse
  ushort_t* kk    = (ushort_t*)kbuf;  // 64MB spans k+v slots
  float*    kv_a  = rbuf;             // split-K part 0 (rbuf dead after part3)
  float*    kv_b  = hbuf;             // split-K part 1 (hbuf dead after mix_cm)

  // scan scratch: reuse hbuf region (dead between mix_tm and ln_fwd#2)
  float* cn = (float*)(W + 26 * MB + 0 * 512 * 1024);
  float* cd = (float*)(W + 26 * MB + 1 * 512 * 1024);
  float* cq = (float*)(W + 26 * MB + 2 * 512 * 1024);
  float* pn = (float*)(W + 26 * MB + 3 * 512 * 1024);
  float* pd = (float*)(W + 26 * MB + 4 * 512 * 1024);
  float* pq = (float*)(W + 26 * MB + 5 * 512 * 1024);

  dim3 tb(32, 8);
  // weight convert + transpose (bf16, [N][K])
  tconv<<<dim3(D_/32, D_/32), tb, 0, stream>>>(tm_kw, w_tmk, D_, D_);
  tconv<<<dim3(D_/32, D_/32), tb, 0, stream>>>(tm_vw, w_tmv, D_, D_);
  tconv<<<dim3(D_/32, D_/32), tb, 0, stream>>>(tm_rw, w_tmr, D_, D_);
  tconv<<<dim3(D_/32, D_/32), tb, 0, stream>>>(out_w, w_out, D_, D_);
  tconv<<<dim3(F_/32, D_/32), tb, 0, stream>>>(cm_kw, w_cmk, D_, F_);
  tconv<<<dim3(D_/32, F_/32), tb, 0, stream>>>(cm_vw, w_cmv, F_, D_);
  tconv<<<dim3(D_/32, D_/32), tb, 0, stream>>>(cm_rw, w_cmr, D_, D_);

  // time-mix path
  ln_fwd<<<M_, 256, 0, stream>>>(x, ln1_g, ln1_b, hbuf, o_hl);
  mix_tm<<<(M_ * D_ / 4) / 256, 256, 0, stream>>>(hbuf, s_tm, tmk, tmv, tmr, xk, xv, xr);
  gemm128<0><<<dim3(M_/128, D_/128), 256, 0, stream>>>(xk, w_tmk, D_, D_, kbuf, nullptr, nullptr, nullptr, nullptr);
  gemm128<0><<<dim3(M_/128, D_/128), 256, 0, stream>>>(xv, w_tmv, D_, D_, vbuf, nullptr, nullptr, nullptr, nullptr);
  gemm128<1><<<dim3(M_/128, D_/128), 256, 0, stream>>>(xr, w_tmr, D_, D_, rbuf, nullptr, nullptr, nullptr, nullptr);

  // chunked parallel WKV scan
  wkv_part1<<<(NC_ * B_ * D_) / 256, 256, 0, stream>>>(kbuf, vbuf, tdec, cn, cd, cq);
  wkv_part2<<<(B_ * D_) / 256, 256, 0, stream>>>(cn, cd, cq, s_num, s_den, s_q, tdec,
                                                 pn, pd, pq, o_num, o_den, o_q);
  wkv_part3<<<(NC_ * B_ * D_) / 256, 256, 0, stream>>>(kbuf, vbuf, rbuf, pn, pd, pq,
                                                       tdec, tfirst, rwkv);

  gemm128<2><<<dim3(M_/128, D_/128), 256, 0, stream>>>(rwkv, w_out, D_, D_, o_x, nullptr, x, nullptr, nullptr);

  // channel-mix path
  ln_fwd<<<M_, 256, 0, stream>>>(o_x, ln2_g, ln2_b, hbuf, o_h2l);
  mix_cm<<<(M_ * D_ / 4) / 256, 256, 0, stream>>>(hbuf, s_cm, cmk, cmr, xk2, xr2);
  // cm_kw: [M,D]@[D,F] -> relu^2 -> bf16 kk   (256-tile pipelined)
  gemm256<1><<<dim3(M_/256, F_/256, 1), 512, 0, stream>>>(xk2, w_cmk, F_, D_, D_/64,
                                                          nullptr, nullptr, kk);
  // cm_vw: [M,F]@[F,D] split-K=2 -> kv_a + kv_b (f32)
  gemm256<0><<<dim3(M_/256, D_/256, 2), 512, 0, stream>>>(kk, w_cmv, D_, F_, F_/128,
                                                          kv_a, kv_b, nullptr);
  // cm_rw + gate + residual: o_x = o_x + sigmoid(acc)*(kv_a+kv_b)
  gemm128<4><<<dim3(M_/128, D_/128), 256, 0, stream>>>(xr2, w_cmr, D_, D_, o_x, nullptr,
                                                       kv_a, o_x, kv_b);
}